// Round 10
// baseline (697.707 us; speedup 1.0000x reference)
//
#include <hip/hip_runtime.h>
#include <hip/hip_bf16.h>
#include <cstdint>

#define BB 128
#define LL 256
#define DD 300
#define HH 512
#define TOUT 511
#define NGATE 2560   // 5*H

typedef __attribute__((ext_vector_type(8))) short bf16x8;
typedef __attribute__((ext_vector_type(4))) float f32x4;

// fast transcendentals: v_rcp_f32 + v_exp_f32 (exp2)
__device__ __forceinline__ float rcpf(float x){ return __builtin_amdgcn_rcpf(x); }
__device__ __forceinline__ float ex2f(float x){ return __builtin_amdgcn_exp2f(x); }
__device__ __forceinline__ float sigf(float x){ return rcpf(1.0f + ex2f(x * -1.44269504f)); }
__device__ __forceinline__ float tanh_fast(float x){ return 1.0f - 2.0f*rcpf(ex2f(x * 2.88539008f) + 1.0f); }

__device__ __forceinline__ void load_lds16(const void* g, void* l) {
  __builtin_amdgcn_global_load_lds(
      (const __attribute__((address_space(1))) unsigned int*)g,
      (__attribute__((address_space(3))) unsigned int*)l, 16, 0, 0);
}

#define VMWAIT(n) asm volatile("s_waitcnt vmcnt(" #n ")" ::: "memory")

// ---- transpose+convert: src f32 [Ksrc][2560] -> dst bf16 [2560][Kdst]
__global__ __launch_bounds__(256) void transpose_cvt(const float* __restrict__ src,
    __hip_bfloat16* __restrict__ dst, int Ksrc, int Kdst, int koff)
{
  __shared__ float t[64][65];
  const int tid = threadIdx.x;
  const int k0 = blockIdx.x * 64;
  const int n0 = blockIdx.y * 64;
  #pragma unroll
  for (int p = 0; p < 16; ++p) {
    int lin = p*256 + tid;
    int ki = lin >> 6, nj = lin & 63;
    t[ki][nj] = (k0 + ki < Ksrc) ? src[(size_t)(k0+ki)*NGATE + n0 + nj] : 0.f;
  }
  __syncthreads();
  #pragma unroll
  for (int p = 0; p < 16; ++p) {
    int lin = p*256 + tid;
    int ni = lin >> 6, kj = lin & 63;
    dst[(size_t)(n0+ni)*Kdst + koff + k0 + kj] = __float2bfloat16(t[kj][ni]);
  }
}

// ---- embedding gather + cvt: A0 bf16 [32768][320]
__global__ void embed_cvt(const int* __restrict__ tok, const float* __restrict__ emb,
                          __hip_bfloat16* __restrict__ A0)
{
  int k = blockIdx.x * 64 + threadIdx.x;
  int r = blockIdx.y * 4 + threadIdx.y;
  int tk = tok[r];
  float v = (k < DD) ? emb[(size_t)tk*DD + k] : 0.f;
  A0[(size_t)r*320 + k] = __float2bfloat16(v);
}

// ======== BIG-LEVEL kernel: A direct-from-global with REGISTER DOUBLE-BUFFER
// (a(t+1) issued at top of tile t -> latency hides under tile t's MFMA phase),
// B-only LDS dbuf 2x20KB. BM=128, BK=32, 8 waves 2(m)x4(n).
// Per tile: [issue a(t+1) glds][stage B(t+1)] -> sched_barrier -> b ds_reads +
// 20 MFMA on a(t) -> vmcnt(0) (issued one full phase ago) -> barrier.
__global__ __launch_bounds__(512) void gemm_cell2(
    const __hip_bfloat16* __restrict__ A, const __hip_bfloat16* __restrict__ Wt,
    int K, const float* __restrict__ bias, const float* __restrict__ cprev,
    float* __restrict__ out, __hip_bfloat16* __restrict__ hout, float* __restrict__ cout,
    int lkshift, int sc, int numM)
{
  constexpr int BUFS = 20480;       // B tile: 320 rows x 32 k bf16 (64B rows)
  __shared__ __align__(16) char lds[2*BUFS];

  const int tid  = threadIdx.x;
  const int lane = tid & 63;
  const int wid  = tid >> 6;
  const int wm   = wid >> 2;        // 0..1 (64-row half)
  const int wn   = wid & 3;         // 0..3 (16 h-col strip)
  const int bid  = blockIdx.x;
  int m, s;
  if (numM >= 8) { m = (bid & 7) + ((bid >> 6) << 3); s = (bid >> 3) & 7; }
  else           { m = bid % numM;  s = bid / numM; }
  const int r0   = m * 128;
  const int n0   = s * 64;
  const size_t rowK = (size_t)K * 2;

  // B staging: 20 x 1KB issues. wid<4: 3 issues, wid>=4: 2 issues.
  const int gi0 = (wid < 4) ? wid*3 : 12 + (wid-4)*2;
  unsigned boff[3];
  #pragma unroll
  for (int i = 0; i < 3; ++i) {
    int gi = gi0 + i;
    int row = gi*16 + (lane >> 2);          // B-tile row (64B each, 4 lanes/row)
    int cg  = (lane & 3) ^ ((row >> 1) & 3);// swizzled src chunk (involution)
    int grow = (row >> 6)*512 + n0 + (row & 63);
    boff[i] = (unsigned)((size_t)grow*rowK) + cg*16;
  }
  const int ldst0 = gi0*1024 + lane*16;

  // A-fragment voffsets: lane holds row (lane&15), k-chunk (lane>>4)*8 of a
  // 16x32 MFMA A-frag = 16 contiguous bytes (HW-verified R8/R9 refcheck).
  unsigned aoff[4];
  #pragma unroll
  for (int mf = 0; mf < 4; ++mf)
    aoff[mf] = (unsigned)((size_t)(r0 + wm*64 + mf*16 + (lane & 15))*rowK)
             + (unsigned)((lane >> 4)*16);

  f32x4 acc[4][5];
  #pragma unroll
  for (int mf = 0; mf < 4; ++mf)
    #pragma unroll
    for (int g5 = 0; g5 < 5; ++g5)
      acc[mf][g5] = (f32x4){0.f,0.f,0.f,0.f};

  const int nk = K >> 5;              // always even (10 or 32)
  auto stage = [&](int buf, int kt){
    char* base = lds + buf*BUFS + ldst0;
    const unsigned kb = (unsigned)kt*64u;
    if (wid < 4) {
      #pragma unroll
      for (int i = 0; i < 3; ++i) load_lds16((const char*)Wt + boff[i] + kb, base + i*1024);
    } else {
      #pragma unroll
      for (int i = 0; i < 2; ++i) load_lds16((const char*)Wt + boff[i] + kb, base + i*1024);
    }
  };

  bf16x8 a_cur[4], a_nxt[4];
  // prologue: B(0) + a(0), drain, barrier
  stage(0, 0);
  #pragma unroll
  for (int mf = 0; mf < 4; ++mf)
    a_cur[mf] = *(const bf16x8*)((const char*)A + aoff[mf]);
  VMWAIT(0);
  __builtin_amdgcn_s_barrier();

  int cur = 0;
  auto body = [&](int tt, bf16x8 (&aU)[4], bf16x8 (&aN)[4]){
    // (1) issue NEXT tile's loads first: a(t+1) regs + B(t+1) stage
    if (tt + 1 < nk) {
      const unsigned kb1 = (unsigned)(tt+1)*64u;
      #pragma unroll
      for (int mf = 0; mf < 4; ++mf)
        aN[mf] = *(const bf16x8*)((const char*)A + aoff[mf] + kb1);
      stage(cur ^ 1, tt + 1);
    }
    __builtin_amdgcn_sched_barrier(0);   // pin issue cluster above compute
    // (2) compute on tile tt (B from LDS buf cur, A from regs)
    const char* Bb = lds + cur*BUFS;
    const int q = lane >> 4;
    bf16x8 b[5];
    #pragma unroll
    for (int g5 = 0; g5 < 5; ++g5) {
      int c = g5*64 + wn*16 + (lane & 15);
      b[g5] = *(const bf16x8*)(Bb + c*64 + ((q ^ ((c >> 1) & 3))*16));
    }
    __builtin_amdgcn_s_setprio(1);
    #pragma unroll
    for (int mf = 0; mf < 4; ++mf)
      #pragma unroll
      for (int g5 = 0; g5 < 5; ++g5)
        acc[mf][g5] = __builtin_amdgcn_mfma_f32_16x16x32_bf16(aU[mf], b[g5], acc[mf][g5], 0, 0, 0);
    __builtin_amdgcn_s_setprio(0);
    // (3) drain next-tile loads (issued one full MFMA phase ago), flip
    if (tt + 1 < nk) VMWAIT(0);
    __builtin_amdgcn_s_barrier();
    cur ^= 1;
  };

  for (int t = 0; t < nk; t += 2) {
    body(t,     a_cur, a_nxt);
    body(t + 1, a_nxt, a_cur);
  }

  // epilogue: fused LSTM cell (fast rcp/exp2)
  const int Lmask = (1 << lkshift) - 1;
  const int jg = n0 + wn*16 + (lane & 15);
  float bia[5];
  #pragma unroll
  for (int g5 = 0; g5 < 5; ++g5) bia[g5] = bias[g5*HH + jg];
  #pragma unroll
  for (int mf = 0; mf < 4; ++mf) {
    #pragma unroll
    for (int v = 0; v < 4; ++v) {
      int rr = r0 + wm*64 + mf*16 + (lane >> 4)*4 + v;
      float gi  = acc[mf][0][v] + bia[0];
      float gfl = acc[mf][1][v] + bia[1];
      float gfr = acc[mf][2][v] + bia[2];
      float go  = acc[mf][3][v] + bia[3];
      float gu  = acc[mf][4][v] + bia[4];
      float cl = 0.f, cr = 0.f;
      if (cprev) {
        cl = cprev[(size_t)(2*rr)*HH + jg];
        cr = cprev[(size_t)(2*rr)*HH + HH + jg];
      }
      float cc = sigf(gi)*tanh_fast(gu) + sigf(gfl)*cl + sigf(gfr)*cr;
      float hh = sigf(go)*tanh_fast(cc);
      int b = rr >> lkshift;
      int t = rr & Lmask;
      out[((size_t)b*TOUT + sc + t)*HH + jg] = hh;
      hout[(size_t)rr*HH + jg] = __float2bfloat16(hh);
      cout[(size_t)rr*HH + jg] = cc;
    }
  }
}

// ======== TAIL kernel (R7 V_A, unchanged): BM=128, BK=32, A+B LDS ========
__global__ __launch_bounds__(512, 4) void gemm_cell(
    const __hip_bfloat16* __restrict__ A, const __hip_bfloat16* __restrict__ Wt,
    int K, const float* __restrict__ bias, const float* __restrict__ cprev,
    float* __restrict__ out, __hip_bfloat16* __restrict__ hout, float* __restrict__ cout,
    int lkshift, int sc, int numM)
{
  constexpr int BUFS = 28672;
  __shared__ __align__(16) char lds[2*BUFS];

  const int tid  = threadIdx.x;
  const int lane = tid & 63;
  const int wid  = tid >> 6;
  const int wm   = wid >> 2;
  const int wn   = wid & 3;
  const int bid  = blockIdx.x;
  int m, s;
  if (numM >= 8) { m = (bid & 7) + ((bid >> 6) << 3); s = (bid >> 3) & 7; }
  else           { m = bid % numM;  s = bid / numM; }
  const int r0   = m * 128;
  const int n0   = s * 64;
  const size_t rowK = (size_t)K * 2;

  const char* gsrc[4];
  int gi0 = (wid < 4) ? wid*4 : 16 + (wid-4)*3;
  #pragma unroll
  for (int i = 0; i < 4; ++i) {
    int gi = gi0 + i;
    int row = (gi < 8) ? gi*16 + (lane >> 2) : (gi-8)*16 + (lane >> 2);
    int cg = (lane & 3) ^ ((row >> 1) & 3);
    if (gi < 8) {
      gsrc[i] = (const char*)A + (size_t)(r0 + row)*rowK + cg*16;
    } else {
      int grow = (row >> 6)*512 + n0 + (row & 63);
      gsrc[i] = (const char*)Wt + (size_t)grow*rowK + cg*16;
    }
  }
  const int ldst0 = gi0*1024 + lane*16;

  f32x4 acc[4][5];
  #pragma unroll
  for (int mf = 0; mf < 4; ++mf)
    #pragma unroll
    for (int g5 = 0; g5 < 5; ++g5)
      acc[mf][g5] = (f32x4){0.f,0.f,0.f,0.f};

  const int nk = K >> 5;
  auto stage = [&](int buf, int kt){
    char* base = lds + buf*BUFS + ldst0;
    const size_t kb = (size_t)kt*64;
    if (wid < 4) {
      #pragma unroll
      for (int i = 0; i < 4; ++i) load_lds16(gsrc[i] + kb, base + i*1024);
    } else {
      #pragma unroll
      for (int i = 0; i < 3; ++i) load_lds16(gsrc[i] + kb, base + i*1024);
    }
  };

  stage(0, 0);
  int cur = 0;
  for (int kt = 0; kt < nk; ++kt) {
    if (kt + 1 < nk) {
      stage(cur ^ 1, kt + 1);
      if (wid < 4) VMWAIT(4); else VMWAIT(3);
    } else {
      VMWAIT(0);
    }
    __builtin_amdgcn_s_barrier();

    const char* Ab = lds + cur*BUFS;
    const char* Bb = Ab + 8192;
    const int q = lane >> 4;
    bf16x8 b[5];
    #pragma unroll
    for (int g5 = 0; g5 < 5; ++g5) {
      int c = g5*64 + wn*16 + (lane & 15);
      b[g5] = *(const bf16x8*)(Bb + c*64 + ((q ^ ((c >> 1) & 3))*16));
    }
    __builtin_amdgcn_s_setprio(1);
    #pragma unroll
    for (int mf = 0; mf < 4; ++mf) {
      int r = wm*64 + mf*16 + (lane & 15);
      bf16x8 av = *(const bf16x8*)(Ab + r*64 + ((q ^ ((r >> 1) & 3))*16));
      #pragma unroll
      for (int g5 = 0; g5 < 5; ++g5)
        acc[mf][g5] = __builtin_amdgcn_mfma_f32_16x16x32_bf16(av, b[g5], acc[mf][g5], 0, 0, 0);
    }
    __builtin_amdgcn_s_setprio(0);
    __builtin_amdgcn_s_barrier();
    cur ^= 1;
  }

  const int Lmask = (1 << lkshift) - 1;
  const int jg = n0 + wn*16 + (lane & 15);
  float bia[5];
  #pragma unroll
  for (int g5 = 0; g5 < 5; ++g5) bia[g5] = bias[g5*HH + jg];
  #pragma unroll
  for (int mf = 0; mf < 4; ++mf) {
    #pragma unroll
    for (int v = 0; v < 4; ++v) {
      int rr = r0 + wm*64 + mf*16 + (lane >> 4)*4 + v;
      float gi  = acc[mf][0][v] + bia[0];
      float gfl = acc[mf][1][v] + bia[1];
      float gfr = acc[mf][2][v] + bia[2];
      float go  = acc[mf][3][v] + bia[3];
      float gu  = acc[mf][4][v] + bia[4];
      float cl = 0.f, cr = 0.f;
      if (cprev) {
        cl = cprev[(size_t)(2*rr)*HH + jg];
        cr = cprev[(size_t)(2*rr)*HH + HH + jg];
      }
      float cc = sigf(gi)*tanh_fast(gu) + sigf(gfl)*cl + sigf(gfr)*cr;
      float hh = sigf(go)*tanh_fast(cc);
      int b = rr >> lkshift;
      int t = rr & Lmask;
      out[((size_t)b*TOUT + sc + t)*HH + jg] = hh;
      hout[(size_t)rr*HH + jg] = __float2bfloat16(hh);
      cout[(size_t)rr*HH + jg] = cc;
    }
  }
}

extern "C" void kernel_launch(void* const* d_in, const int* in_sizes, int n_in,
                              void* d_out, int out_size, void* d_ws, size_t ws_size,
                              hipStream_t stream) {
  (void)in_sizes; (void)n_in; (void)out_size; (void)ws_size;
  const int*   tok  = (const int*)d_in[0];
  const float* emb  = (const float*)d_in[1];
  const float* Wx   = (const float*)d_in[2];
  const float* Ul   = (const float*)d_in[3];
  const float* Ur   = (const float*)d_in[4];
  const float* bias = (const float*)d_in[5];
  float* out = (float*)d_out;

  char* ws = (char*)d_ws;
  size_t off = 0;
  __hip_bfloat16* Wb0t = (__hip_bfloat16*)(ws + off); off += (size_t)NGATE*320*2;
  __hip_bfloat16* Wb1t = (__hip_bfloat16*)(ws + off); off += (size_t)NGATE*1024*2;
  __hip_bfloat16* hA   = (__hip_bfloat16*)(ws + off); off += (size_t)32768*HH*2;
  __hip_bfloat16* hB   = (__hip_bfloat16*)(ws + off); off += (size_t)16384*HH*2;
  float*          cA   = (float*)(ws + off);          off += (size_t)32768*HH*4;
  float*          cB   = (float*)(ws + off);          off += (size_t)16384*HH*4;
  __hip_bfloat16* A0   = (__hip_bfloat16*)cB;   // alias: A0 dead before cB first written

  transpose_cvt<<<dim3(5, 40), 256, 0, stream>>>(Wx, Wb0t, DD, 320, 0);
  transpose_cvt<<<dim3(8, 40), 256, 0, stream>>>(Ul, Wb1t, HH, 1024, 0);
  transpose_cvt<<<dim3(8, 40), 256, 0, stream>>>(Ur, Wb1t, HH, 1024, 512);
  embed_cvt<<<dim3(5, 8192), dim3(64,4), 0, stream>>>(tok, emb, A0);

  // level 0: M=32768, K=320 (nk=10)
  gemm_cell2<<<(32768/128)*8, 512, 0, stream>>>(A0, Wb0t, 320, bias, nullptr,
                                                out, hA, cA, 8, 0, 32768/128);
  // levels 1..8
  for (int k = 1; k <= 8; ++k) {
    int M = 32768 >> k;
    int sc = HH - (HH >> k);
    const __hip_bfloat16* Ain = (k & 1) ? hA : hB;
    __hip_bfloat16*       hO  = (k & 1) ? hB : hA;
    const float*          cI  = (k & 1) ? cA : cB;
    float*                cO  = (k & 1) ? cB : cA;
    int numM = M / 128;
    if (M >= 8192) {
      gemm_cell2<<<numM*8, 512, 0, stream>>>(Ain, Wb1t, 1024, bias, cI,
                                             out, hO, cO, 8 - k, sc, numM);
    } else {
      gemm_cell<<<numM*8, 512, 0, stream>>>(Ain, Wb1t, 1024, bias, cI,
                                            out, hO, cO, 8 - k, sc, numM);
    }
  }
}

// Round 11
// 614.634 us; speedup vs baseline: 1.1352x; 1.1352x over previous
//
#include <hip/hip_runtime.h>
#include <hip/hip_bf16.h>
#include <hip/hip_cooperative_groups.h>
#include <cstdint>

namespace cgrp = cooperative_groups;

#define BB 128
#define LL 256
#define DD 300
#define HH 512
#define TOUT 511
#define NGATE 2560   // 5*H

typedef __attribute__((ext_vector_type(8))) short bf16x8;
typedef __attribute__((ext_vector_type(4))) float f32x4;

// fast transcendentals: v_rcp_f32 + v_exp_f32 (exp2)
__device__ __forceinline__ float rcpf(float x){ return __builtin_amdgcn_rcpf(x); }
__device__ __forceinline__ float ex2f(float x){ return __builtin_amdgcn_exp2f(x); }
__device__ __forceinline__ float sigf(float x){ return rcpf(1.0f + ex2f(x * -1.44269504f)); }
__device__ __forceinline__ float tanh_fast(float x){ return 1.0f - 2.0f*rcpf(ex2f(x * 2.88539008f) + 1.0f); }

__device__ __forceinline__ void load_lds16(const void* g, void* l) {
  __builtin_amdgcn_global_load_lds(
      (const __attribute__((address_space(1))) unsigned int*)g,
      (__attribute__((address_space(3))) unsigned int*)l, 16, 0, 0);
}

#define VMWAIT(n) asm volatile("s_waitcnt vmcnt(" #n ")" ::: "memory")

// ---- fused weight prep: z=0 Wx->Wb0t[320], z=1 Ul->Wb1t[0:512), z=2 Ur->Wb1t[512:1024)
__global__ __launch_bounds__(256) void prep_weights(
    const float* __restrict__ Wx, const float* __restrict__ Ul, const float* __restrict__ Ur,
    __hip_bfloat16* __restrict__ Wb0t, __hip_bfloat16* __restrict__ Wb1t)
{
  const int z = blockIdx.z;
  const float* src; __hip_bfloat16* dst; int Ksrc, Kdst, koff;
  if (z == 0) { if (blockIdx.x >= 5) return; src = Wx; dst = Wb0t; Ksrc = DD; Kdst = 320; koff = 0; }
  else if (z == 1) { src = Ul; dst = Wb1t; Ksrc = HH; Kdst = 1024; koff = 0; }
  else { src = Ur; dst = Wb1t; Ksrc = HH; Kdst = 1024; koff = 512; }

  __shared__ float t[64][65];
  const int tid = threadIdx.x;
  const int k0 = blockIdx.x * 64;
  const int n0 = blockIdx.y * 64;
  #pragma unroll
  for (int p = 0; p < 16; ++p) {
    int lin = p*256 + tid;
    int ki = lin >> 6, nj = lin & 63;
    t[ki][nj] = (k0 + ki < Ksrc) ? src[(size_t)(k0+ki)*NGATE + n0 + nj] : 0.f;
  }
  __syncthreads();
  #pragma unroll
  for (int p = 0; p < 16; ++p) {
    int lin = p*256 + tid;
    int ni = lin >> 6, kj = lin & 63;
    dst[(size_t)(n0+ni)*Kdst + koff + k0 + kj] = __float2bfloat16(t[kj][ni]);
  }
}

// ---- embedding gather + cvt: A0 bf16 [32768][320]
__global__ void embed_cvt(const int* __restrict__ tok, const float* __restrict__ emb,
                          __hip_bfloat16* __restrict__ A0)
{
  int k = blockIdx.x * 64 + threadIdx.x;
  int r = blockIdx.y * 4 + threadIdx.y;
  int tk = tok[r];
  float v = (k < DD) ? emb[(size_t)tk*DD + k] : 0.f;
  A0[(size_t)r*320 + k] = __float2bfloat16(v);
}

// ======== R7 V_A kernel (proven): BM=128, BK=32, A+B LDS 2x28KB ========
__global__ __launch_bounds__(512, 4) void gemm_cell(
    const __hip_bfloat16* __restrict__ A, const __hip_bfloat16* __restrict__ Wt,
    int K, const float* __restrict__ bias, const float* __restrict__ cprev,
    float* __restrict__ out, __hip_bfloat16* __restrict__ hout, float* __restrict__ cout,
    int lkshift, int sc, int numM)
{
  constexpr int BUFS = 28672;
  __shared__ __align__(16) char lds[2*BUFS];

  const int tid  = threadIdx.x;
  const int lane = tid & 63;
  const int wid  = tid >> 6;
  const int wm   = wid >> 2;
  const int wn   = wid & 3;
  const int bid  = blockIdx.x;
  int m, s;
  if (numM >= 8) { m = (bid & 7) + ((bid >> 6) << 3); s = (bid >> 3) & 7; }
  else           { m = bid % numM;  s = bid / numM; }
  const int r0   = m * 128;
  const int n0   = s * 64;
  const size_t rowK = (size_t)K * 2;

  const char* gsrc[4];
  int gi0 = (wid < 4) ? wid*4 : 16 + (wid-4)*3;
  #pragma unroll
  for (int i = 0; i < 4; ++i) {
    int gi = gi0 + i;
    int row = (gi < 8) ? gi*16 + (lane >> 2) : (gi-8)*16 + (lane >> 2);
    int cs = (lane & 3) ^ ((row >> 1) & 3);
    if (gi < 8) {
      gsrc[i] = (const char*)A + (size_t)(r0 + row)*rowK + cs*16;
    } else {
      int grow = (row >> 6)*512 + n0 + (row & 63);
      gsrc[i] = (const char*)Wt + (size_t)grow*rowK + cs*16;
    }
  }
  const int ldst0 = gi0*1024 + lane*16;

  f32x4 acc[4][5];
  #pragma unroll
  for (int mf = 0; mf < 4; ++mf)
    #pragma unroll
    for (int g5 = 0; g5 < 5; ++g5)
      acc[mf][g5] = (f32x4){0.f,0.f,0.f,0.f};

  const int nk = K >> 5;
  auto stage = [&](int buf, int kt){
    char* base = lds + buf*BUFS + ldst0;
    const size_t kb = (size_t)kt*64;
    if (wid < 4) {
      #pragma unroll
      for (int i = 0; i < 4; ++i) load_lds16(gsrc[i] + kb, base + i*1024);
    } else {
      #pragma unroll
      for (int i = 0; i < 3; ++i) load_lds16(gsrc[i] + kb, base + i*1024);
    }
  };

  stage(0, 0);
  int cur = 0;
  for (int kt = 0; kt < nk; ++kt) {
    if (kt + 1 < nk) {
      stage(cur ^ 1, kt + 1);
      if (wid < 4) VMWAIT(4); else VMWAIT(3);
    } else {
      VMWAIT(0);
    }
    __builtin_amdgcn_s_barrier();

    const char* Ab = lds + cur*BUFS;
    const char* Bb = Ab + 8192;
    const int q = lane >> 4;
    bf16x8 b[5];
    #pragma unroll
    for (int g5 = 0; g5 < 5; ++g5) {
      int c = g5*64 + wn*16 + (lane & 15);
      b[g5] = *(const bf16x8*)(Bb + c*64 + ((q ^ ((c >> 1) & 3))*16));
    }
    __builtin_amdgcn_s_setprio(1);
    #pragma unroll
    for (int mf = 0; mf < 4; ++mf) {
      int r = wm*64 + mf*16 + (lane & 15);
      bf16x8 av = *(const bf16x8*)(Ab + r*64 + ((q ^ ((r >> 1) & 3))*16));
      #pragma unroll
      for (int g5 = 0; g5 < 5; ++g5)
        acc[mf][g5] = __builtin_amdgcn_mfma_f32_16x16x32_bf16(av, b[g5], acc[mf][g5], 0, 0, 0);
    }
    __builtin_amdgcn_s_setprio(0);
    __builtin_amdgcn_s_barrier();
    cur ^= 1;
  }

  const int Lmask = (1 << lkshift) - 1;
  const int jg = n0 + wn*16 + (lane & 15);
  float bia[5];
  #pragma unroll
  for (int g5 = 0; g5 < 5; ++g5) bia[g5] = bias[g5*HH + jg];
  #pragma unroll
  for (int mf = 0; mf < 4; ++mf) {
    #pragma unroll
    for (int v = 0; v < 4; ++v) {
      int rr = r0 + wm*64 + mf*16 + (lane >> 4)*4 + v;
      float gi  = acc[mf][0][v] + bia[0];
      float gfl = acc[mf][1][v] + bia[1];
      float gfr = acc[mf][2][v] + bia[2];
      float go  = acc[mf][3][v] + bia[3];
      float gu  = acc[mf][4][v] + bia[4];
      float cl = 0.f, cr = 0.f;
      if (cprev) {
        cl = cprev[(size_t)(2*rr)*HH + jg];
        cr = cprev[(size_t)(2*rr)*HH + HH + jg];
      }
      float cc = sigf(gi)*tanh_fast(gu) + sigf(gfl)*cl + sigf(gfr)*cr;
      float hh = sigf(go)*tanh_fast(cc);
      int b = rr >> lkshift;
      int t = rr & Lmask;
      out[((size_t)b*TOUT + sc + t)*HH + jg] = hh;
      hout[(size_t)rr*HH + jg] = __float2bfloat16(hh);
      cout[(size_t)rr*HH + jg] = cc;
    }
  }
}

// ---- one 128x64h tile of a K=1024 level (same body as gemm_cell, K fixed)
__device__ __forceinline__ void tile_gemm_1024(
    char* lds, const __hip_bfloat16* __restrict__ A, const __hip_bfloat16* __restrict__ Wt,
    const float* __restrict__ bias, const float* __restrict__ cprev,
    float* __restrict__ out, __hip_bfloat16* __restrict__ hout, float* __restrict__ cout,
    int lkshift, int sc, int r0, int n0, int lane, int wid, int wm, int wn)
{
  constexpr int BUFS = 28672;
  constexpr size_t rowK = 2048;
  const char* gsrc[4];
  int gi0 = (wid < 4) ? wid*4 : 16 + (wid-4)*3;
  #pragma unroll
  for (int i = 0; i < 4; ++i) {
    int gi = gi0 + i;
    int row = (gi < 8) ? gi*16 + (lane >> 2) : (gi-8)*16 + (lane >> 2);
    int cs = (lane & 3) ^ ((row >> 1) & 3);
    if (gi < 8) {
      gsrc[i] = (const char*)A + (size_t)(r0 + row)*rowK + cs*16;
    } else {
      int grow = (row >> 6)*512 + n0 + (row & 63);
      gsrc[i] = (const char*)Wt + (size_t)grow*rowK + cs*16;
    }
  }
  const int ldst0 = gi0*1024 + lane*16;

  f32x4 acc[4][5];
  #pragma unroll
  for (int mf = 0; mf < 4; ++mf)
    #pragma unroll
    for (int g5 = 0; g5 < 5; ++g5)
      acc[mf][g5] = (f32x4){0.f,0.f,0.f,0.f};

  auto stage = [&](int buf, int kt){
    char* base = lds + buf*BUFS + ldst0;
    const size_t kb = (size_t)kt*64;
    if (wid < 4) {
      #pragma unroll
      for (int i = 0; i < 4; ++i) load_lds16(gsrc[i] + kb, base + i*1024);
    } else {
      #pragma unroll
      for (int i = 0; i < 3; ++i) load_lds16(gsrc[i] + kb, base + i*1024);
    }
  };

  stage(0, 0);
  int cur = 0;
  for (int kt = 0; kt < 32; ++kt) {
    if (kt + 1 < 32) {
      stage(cur ^ 1, kt + 1);
      if (wid < 4) VMWAIT(4); else VMWAIT(3);
    } else {
      VMWAIT(0);
    }
    __builtin_amdgcn_s_barrier();

    const char* Ab = lds + cur*BUFS;
    const char* Bb = Ab + 8192;
    const int q = lane >> 4;
    bf16x8 b[5];
    #pragma unroll
    for (int g5 = 0; g5 < 5; ++g5) {
      int c = g5*64 + wn*16 + (lane & 15);
      b[g5] = *(const bf16x8*)(Bb + c*64 + ((q ^ ((c >> 1) & 3))*16));
    }
    __builtin_amdgcn_s_setprio(1);
    #pragma unroll
    for (int mf = 0; mf < 4; ++mf) {
      int r = wm*64 + mf*16 + (lane & 15);
      bf16x8 av = *(const bf16x8*)(Ab + r*64 + ((q ^ ((r >> 1) & 3))*16));
      #pragma unroll
      for (int g5 = 0; g5 < 5; ++g5)
        acc[mf][g5] = __builtin_amdgcn_mfma_f32_16x16x32_bf16(av, b[g5], acc[mf][g5], 0, 0, 0);
    }
    __builtin_amdgcn_s_setprio(0);
    __builtin_amdgcn_s_barrier();
    cur ^= 1;
  }

  const int Lmask = (1 << lkshift) - 1;
  const int jg = n0 + wn*16 + (lane & 15);
  float bia[5];
  #pragma unroll
  for (int g5 = 0; g5 < 5; ++g5) bia[g5] = bias[g5*HH + jg];
  #pragma unroll
  for (int mf = 0; mf < 4; ++mf) {
    #pragma unroll
    for (int v = 0; v < 4; ++v) {
      int rr = r0 + wm*64 + mf*16 + (lane >> 4)*4 + v;
      float gi  = acc[mf][0][v] + bia[0];
      float gfl = acc[mf][1][v] + bia[1];
      float gfr = acc[mf][2][v] + bia[2];
      float go  = acc[mf][3][v] + bia[3];
      float gu  = acc[mf][4][v] + bia[4];
      float cl = cprev[(size_t)(2*rr)*HH + jg];
      float cr = cprev[(size_t)(2*rr)*HH + HH + jg];
      float cc = sigf(gi)*tanh_fast(gu) + sigf(gfl)*cl + sigf(gfr)*cr;
      float hh = sigf(go)*tanh_fast(cc);
      int b = rr >> lkshift;
      int t = rr & Lmask;
      out[((size_t)b*TOUT + sc + t)*HH + jg] = hh;
      hout[(size_t)rr*HH + jg] = __float2bfloat16(hh);
      cout[(size_t)rr*HH + jg] = cc;
    }
  }
}

// ======== cooperative tail: levels 3..8 in ONE dispatch, grid.sync between ====
__global__ __launch_bounds__(512, 2) void tail_coop(
    __hip_bfloat16* hA, __hip_bfloat16* hB, float* cA, float* cB,
    const __hip_bfloat16* __restrict__ Wt, const float* __restrict__ bias,
    float* __restrict__ out)
{
  __shared__ __align__(16) char lds[57344];
  const int tid  = threadIdx.x;
  const int lane = tid & 63;
  const int wid  = tid >> 6;
  const int wm   = wid >> 2;
  const int wn   = wid & 3;
  cgrp::grid_group g = cgrp::this_grid();

  for (int k = 3; k <= 8; ++k) {
    const __hip_bfloat16* Ain = (k & 1) ? hA : hB;
    __hip_bfloat16*       hO  = (k & 1) ? hB : hA;
    const float*          cI  = (k & 1) ? cA : cB;
    float*                cO  = (k & 1) ? cB : cA;
    const int M    = 32768 >> k;
    const int numM = M >> 7;
    const int tiles = numM * 8;
    const int sc   = HH - (HH >> k);
    const int lks  = 8 - k;
    // tile = s*numM + m: same-m strips land on one XCD when numM%8==0
    for (int tile = blockIdx.x; tile < tiles; tile += gridDim.x) {
      int m = tile % numM, s = tile / numM;
      tile_gemm_1024(lds, Ain, Wt, bias, cI, out, hO, cO, lks, sc,
                     m*128, s*64, lane, wid, wm, wn);
    }
    g.sync();
  }
}

extern "C" void kernel_launch(void* const* d_in, const int* in_sizes, int n_in,
                              void* d_out, int out_size, void* d_ws, size_t ws_size,
                              hipStream_t stream) {
  (void)in_sizes; (void)n_in; (void)out_size; (void)ws_size;
  const int*   tok  = (const int*)d_in[0];
  const float* emb  = (const float*)d_in[1];
  const float* Wx   = (const float*)d_in[2];
  const float* Ul   = (const float*)d_in[3];
  const float* Ur   = (const float*)d_in[4];
  const float* bias = (const float*)d_in[5];
  float* out = (float*)d_out;

  char* ws = (char*)d_ws;
  size_t off = 0;
  __hip_bfloat16* Wb0t = (__hip_bfloat16*)(ws + off); off += (size_t)NGATE*320*2;
  __hip_bfloat16* Wb1t = (__hip_bfloat16*)(ws + off); off += (size_t)NGATE*1024*2;
  __hip_bfloat16* hA   = (__hip_bfloat16*)(ws + off); off += (size_t)32768*HH*2;
  __hip_bfloat16* hB   = (__hip_bfloat16*)(ws + off); off += (size_t)16384*HH*2;
  float*          cA   = (float*)(ws + off);          off += (size_t)32768*HH*4;
  float*          cB   = (float*)(ws + off);          off += (size_t)16384*HH*4;
  __hip_bfloat16* A0   = (__hip_bfloat16*)cB;   // alias: A0 dead before cB first written

  prep_weights<<<dim3(8, 40, 3), 256, 0, stream>>>(Wx, Ul, Ur, Wb0t, Wb1t);
  embed_cvt<<<dim3(5, 8192), dim3(64,4), 0, stream>>>(tok, emb, A0);

  // levels 0..2: proven R7 kernel
  gemm_cell<<<(32768/128)*8, 512, 0, stream>>>(A0, Wb0t, 320, bias, nullptr,
                                               out, hA, cA, 8, 0, 32768/128);
  gemm_cell<<<(16384/128)*8, 512, 0, stream>>>(hA, Wb1t, 1024, bias, cA,
                                               out, hB, cB, 7, 256, 16384/128);
  gemm_cell<<<(8192/128)*8, 512, 0, stream>>>(hB, Wb1t, 1024, bias, cB,
                                              out, hA, cA, 6, 384, 8192/128);

  // levels 3..8: one cooperative dispatch
  void* kargs[] = {(void*)&hA, (void*)&hB, (void*)&cA, (void*)&cB,
                   (void*)&Wb1t, (void*)&bias, (void*)&out};
  hipLaunchCooperativeKernel(tail_coop, dim3(256), dim3(512), kargs, 0, stream);
}

// Round 12
// 463.069 us; speedup vs baseline: 1.5067x; 1.3273x over previous
//
#include <hip/hip_runtime.h>
#include <hip/hip_bf16.h>
#include <cstdint>

#define BB 128
#define LL 256
#define DD 300
#define HH 512
#define TOUT 511
#define NGATE 2560   // 5*H

typedef __attribute__((ext_vector_type(8))) short bf16x8;
typedef __attribute__((ext_vector_type(4))) float f32x4;

__device__ __forceinline__ float rcpf(float x){ return __builtin_amdgcn_rcpf(x); }
__device__ __forceinline__ float ex2f(float x){ return __builtin_amdgcn_exp2f(x); }
__device__ __forceinline__ float sigf(float x){ return rcpf(1.0f + ex2f(x * -1.44269504f)); }
__device__ __forceinline__ float tanh_fast(float x){ return 1.0f - 2.0f*rcpf(ex2f(x * 2.88539008f) + 1.0f); }

__device__ __forceinline__ void load_lds16(const void* g, void* l) {
  __builtin_amdgcn_global_load_lds(
      (const __attribute__((address_space(1))) unsigned int*)g,
      (__attribute__((address_space(3))) unsigned int*)l, 16, 0, 0);
}

#define VMWAIT(n) asm volatile("s_waitcnt vmcnt(" #n ")" ::: "memory")
#define LGKM0()   asm volatile("s_waitcnt lgkmcnt(0)" ::: "memory")

// ---- fused weight prep
__global__ __launch_bounds__(256) void prep_weights(
    const float* __restrict__ Wx, const float* __restrict__ Ul, const float* __restrict__ Ur,
    __hip_bfloat16* __restrict__ Wb0t, __hip_bfloat16* __restrict__ Wb1t)
{
  const int z = blockIdx.z;
  const float* src; __hip_bfloat16* dst; int Ksrc, Kdst, koff;
  if (z == 0) { if (blockIdx.x >= 5) return; src = Wx; dst = Wb0t; Ksrc = DD; Kdst = 320; koff = 0; }
  else if (z == 1) { src = Ul; dst = Wb1t; Ksrc = HH; Kdst = 1024; koff = 0; }
  else { src = Ur; dst = Wb1t; Ksrc = HH; Kdst = 1024; koff = 512; }

  __shared__ float t[64][65];
  const int tid = threadIdx.x;
  const int k0 = blockIdx.x * 64;
  const int n0 = blockIdx.y * 64;
  #pragma unroll
  for (int p = 0; p < 16; ++p) {
    int lin = p*256 + tid;
    int ki = lin >> 6, nj = lin & 63;
    t[ki][nj] = (k0 + ki < Ksrc) ? src[(size_t)(k0+ki)*NGATE + n0 + nj] : 0.f;
  }
  __syncthreads();
  #pragma unroll
  for (int p = 0; p < 16; ++p) {
    int lin = p*256 + tid;
    int ni = lin >> 6, kj = lin & 63;
    dst[(size_t)(n0+ni)*Kdst + koff + k0 + kj] = __float2bfloat16(t[kj][ni]);
  }
}

__global__ void embed_cvt(const int* __restrict__ tok, const float* __restrict__ emb,
                          __hip_bfloat16* __restrict__ A0)
{
  int k = blockIdx.x * 64 + threadIdx.x;
  int r = blockIdx.y * 4 + threadIdx.y;
  int tk = tok[r];
  float v = (k < DD) ? emb[(size_t)tk*DD + k] : 0.f;
  A0[(size_t)r*320 + k] = __float2bfloat16(v);
}

// ======== BIG kernel (L0-L2): BM=256 x 64h, half-tile ring (4 slots, 3 ahead),
// counted vmcnt, 1 barrier + lgkmcnt(0) per half-tile, 2 MFMA phases.
__global__ __launch_bounds__(512, 2) void gemm_big(
    const __hip_bfloat16* __restrict__ A, const __hip_bfloat16* __restrict__ Wt,
    int K, const float* __restrict__ bias, const float* __restrict__ cprev,
    float* __restrict__ out, __hip_bfloat16* __restrict__ hout, float* __restrict__ cout,
    int lkshift, int sc)
{
  constexpr int HBYT = 36864;   // A-half 256x32 (16KB) + B-half 320x32 (20KB)
  __shared__ __align__(16) char lds[4*HBYT];

  const int tid  = threadIdx.x;
  const int lane = tid & 63;
  const int wid  = tid >> 6;
  const int wm   = wid >> 2;        // 0..1 (128-row half)
  const int wn   = wid & 3;         // 0..3 (16 h-col strip)
  const int bid  = blockIdx.x;
  const int m    = (bid & 7) + ((bid >> 6) << 3);   // XCD co-location
  const int s    = (bid >> 3) & 7;
  const int r0   = m * 256;
  const int n0   = s * 64;
  const size_t rowK = (size_t)K * 2;

  // staging: 36 x 1KB issues/half (A: gi 0-15, B: gi 16-35). wid<4:5, wid>=4:4.
  const int gi0 = (wid < 4) ? wid*5 : 20 + (wid-4)*4;
  const char* gsrc[5];
  #pragma unroll
  for (int i = 0; i < 5; ++i) {
    int gi = gi0 + i;
    if (gi < 16) {
      int row = gi*16 + (lane >> 2);
      int cs  = (lane & 3) ^ ((row >> 1) & 3);
      gsrc[i] = (const char*)A + (size_t)(r0 + row)*rowK + cs*16;
    } else {
      int rowb = (gi-16)*16 + (lane >> 2);
      int cs   = (lane & 3) ^ ((rowb >> 1) & 3);
      int grow = (rowb >> 6)*512 + n0 + (rowb & 63);
      gsrc[i] = (const char*)Wt + (size_t)grow*rowK + cs*16;
    }
  }
  const int ldst0 = gi0*1024 + lane*16;   // A ends at 16KB so gi*1024 works for both

  f32x4 acc[8][5];
  #pragma unroll
  for (int mf = 0; mf < 8; ++mf)
    #pragma unroll
    for (int g5 = 0; g5 < 5; ++g5)
      acc[mf][g5] = (f32x4){0.f,0.f,0.f,0.f};

  const int nt = K >> 5;   // half-tiles (10 or 32)
  auto stage = [&](int t){
    char* base = lds + (size_t)(t & 3)*HBYT + ldst0;
    const size_t kb = (size_t)t*64;
    if (wid < 4) {
      #pragma unroll
      for (int i = 0; i < 5; ++i) load_lds16(gsrc[i] + kb, base + i*1024);
    } else {
      #pragma unroll
      for (int i = 0; i < 4; ++i) load_lds16(gsrc[i] + kb, base + i*1024);
    }
  };

  stage(0); stage(1); stage(2);     // 3-deep prologue

  for (int t = 0; t < nt; ++t) {
    // counted wait: drain half t, leave t+1/t+2 in flight (FIFO, per-wave)
    if (t + 2 < nt)      { if (wid < 4) VMWAIT(10); else VMWAIT(8); }
    else if (t + 1 < nt) { if (wid < 4) VMWAIT(5);  else VMWAIT(4); }
    else                 { VMWAIT(0); }
    LGKM0();                           // own ds_reads of old slots complete
    __builtin_amdgcn_s_barrier();      // all waves: half t landed, old reads done

    const char* Ab = lds + (size_t)(t & 3)*HBYT;
    const char* Bb = Ab + 16384;
    const int q = lane >> 4;

    bf16x8 b[5];
    #pragma unroll
    for (int g5 = 0; g5 < 5; ++g5) {
      int c = g5*64 + wn*16 + (lane & 15);
      b[g5] = *(const bf16x8*)(Bb + c*64 + ((q ^ ((c >> 1) & 3))*16));
    }
    bf16x8 a[4];
    #pragma unroll
    for (int i = 0; i < 4; ++i) {
      int r = wm*128 + i*16 + (lane & 15);
      a[i] = *(const bf16x8*)(Ab + r*64 + ((q ^ ((r >> 1) & 3))*16));
    }
    if (t + 3 < nt) stage(t + 3);      // issue writes to slot (t-1)&3: safe post-barrier
    __builtin_amdgcn_sched_barrier(0);
    __builtin_amdgcn_s_setprio(1);
    #pragma unroll
    for (int mf = 0; mf < 4; ++mf)
      #pragma unroll
      for (int g5 = 0; g5 < 5; ++g5)
        acc[mf][g5] = __builtin_amdgcn_mfma_f32_16x16x32_bf16(a[mf], b[g5], acc[mf][g5], 0, 0, 0);
    __builtin_amdgcn_s_setprio(0);

    #pragma unroll
    for (int i = 0; i < 4; ++i) {
      int r = wm*128 + (4+i)*16 + (lane & 15);
      a[i] = *(const bf16x8*)(Ab + r*64 + ((q ^ ((r >> 1) & 3))*16));
    }
    __builtin_amdgcn_sched_barrier(0);
    __builtin_amdgcn_s_setprio(1);
    #pragma unroll
    for (int mf = 0; mf < 4; ++mf)
      #pragma unroll
      for (int g5 = 0; g5 < 5; ++g5)
        acc[4+mf][g5] = __builtin_amdgcn_mfma_f32_16x16x32_bf16(a[mf], b[g5], acc[4+mf][g5], 0, 0, 0);
    __builtin_amdgcn_s_setprio(0);
  }

  // epilogue
  const int Lmask = (1 << lkshift) - 1;
  const int jg = n0 + wn*16 + (lane & 15);
  float bia[5];
  #pragma unroll
  for (int g5 = 0; g5 < 5; ++g5) bia[g5] = bias[g5*HH + jg];
  #pragma unroll
  for (int mf = 0; mf < 8; ++mf) {
    #pragma unroll
    for (int v = 0; v < 4; ++v) {
      int rr = r0 + wm*128 + mf*16 + (lane >> 4)*4 + v;
      float gi  = acc[mf][0][v] + bia[0];
      float gfl = acc[mf][1][v] + bia[1];
      float gfr = acc[mf][2][v] + bia[2];
      float go  = acc[mf][3][v] + bia[3];
      float gu  = acc[mf][4][v] + bia[4];
      float cl = 0.f, cr = 0.f;
      if (cprev) {
        cl = cprev[(size_t)(2*rr)*HH + jg];
        cr = cprev[(size_t)(2*rr)*HH + HH + jg];
      }
      float cc = sigf(gi)*tanh_fast(gu) + sigf(gfl)*cl + sigf(gfr)*cr;
      float hh = sigf(go)*tanh_fast(cc);
      int b = rr >> lkshift;
      int t = rr & Lmask;
      out[((size_t)b*TOUT + sc + t)*HH + jg] = hh;
      hout[(size_t)rr*HH + jg] = __float2bfloat16(hh);
      cout[(size_t)rr*HH + jg] = cc;
    }
  }
}

// ======== TAIL kernel (R7 V_A, proven): BM=128, BK=32, A+B LDS 2x28KB ========
__global__ __launch_bounds__(512, 4) void gemm_cell(
    const __hip_bfloat16* __restrict__ A, const __hip_bfloat16* __restrict__ Wt,
    int K, const float* __restrict__ bias, const float* __restrict__ cprev,
    float* __restrict__ out, __hip_bfloat16* __restrict__ hout, float* __restrict__ cout,
    int lkshift, int sc, int numM)
{
  constexpr int BUFS = 28672;
  __shared__ __align__(16) char lds[2*BUFS];

  const int tid  = threadIdx.x;
  const int lane = tid & 63;
  const int wid  = tid >> 6;
  const int wm   = wid >> 2;
  const int wn   = wid & 3;
  const int bid  = blockIdx.x;
  int m, s;
  if (numM >= 8) { m = (bid & 7) + ((bid >> 6) << 3); s = (bid >> 3) & 7; }
  else           { m = bid % numM;  s = bid / numM; }
  const int r0   = m * 128;
  const int n0   = s * 64;
  const size_t rowK = (size_t)K * 2;

  const char* gsrc[4];
  int gi0 = (wid < 4) ? wid*4 : 16 + (wid-4)*3;
  #pragma unroll
  for (int i = 0; i < 4; ++i) {
    int gi = gi0 + i;
    int row = (gi < 8) ? gi*16 + (lane >> 2) : (gi-8)*16 + (lane >> 2);
    int cs = (lane & 3) ^ ((row >> 1) & 3);
    if (gi < 8) {
      gsrc[i] = (const char*)A + (size_t)(r0 + row)*rowK + cs*16;
    } else {
      int grow = (row >> 6)*512 + n0 + (row & 63);
      gsrc[i] = (const char*)Wt + (size_t)grow*rowK + cs*16;
    }
  }
  const int ldst0 = gi0*1024 + lane*16;

  f32x4 acc[4][5];
  #pragma unroll
  for (int mf = 0; mf < 4; ++mf)
    #pragma unroll
    for (int g5 = 0; g5 < 5; ++g5)
      acc[mf][g5] = (f32x4){0.f,0.f,0.f,0.f};

  const int nk = K >> 5;
  auto stage = [&](int buf, int kt){
    char* base = lds + buf*BUFS + ldst0;
    const size_t kb = (size_t)kt*64;
    if (wid < 4) {
      #pragma unroll
      for (int i = 0; i < 4; ++i) load_lds16(gsrc[i] + kb, base + i*1024);
    } else {
      #pragma unroll
      for (int i = 0; i < 3; ++i) load_lds16(gsrc[i] + kb, base + i*1024);
    }
  };

  stage(0, 0);
  int cur = 0;
  for (int kt = 0; kt < nk; ++kt) {
    if (kt + 1 < nk) {
      stage(cur ^ 1, kt + 1);
      if (wid < 4) VMWAIT(4); else VMWAIT(3);
    } else {
      VMWAIT(0);
    }
    __builtin_amdgcn_s_barrier();

    const char* Ab = lds + cur*BUFS;
    const char* Bb = Ab + 8192;
    const int q = lane >> 4;
    bf16x8 b[5];
    #pragma unroll
    for (int g5 = 0; g5 < 5; ++g5) {
      int c = g5*64 + wn*16 + (lane & 15);
      b[g5] = *(const bf16x8*)(Bb + c*64 + ((q ^ ((c >> 1) & 3))*16));
    }
    __builtin_amdgcn_s_setprio(1);
    #pragma unroll
    for (int mf = 0; mf < 4; ++mf) {
      int r = wm*64 + mf*16 + (lane & 15);
      bf16x8 av = *(const bf16x8*)(Ab + r*64 + ((q ^ ((r >> 1) & 3))*16));
      #pragma unroll
      for (int g5 = 0; g5 < 5; ++g5)
        acc[mf][g5] = __builtin_amdgcn_mfma_f32_16x16x32_bf16(av, b[g5], acc[mf][g5], 0, 0, 0);
    }
    __builtin_amdgcn_s_setprio(0);
    __builtin_amdgcn_s_barrier();
    cur ^= 1;
  }

  const int Lmask = (1 << lkshift) - 1;
  const int jg = n0 + wn*16 + (lane & 15);
  float bia[5];
  #pragma unroll
  for (int g5 = 0; g5 < 5; ++g5) bia[g5] = bias[g5*HH + jg];
  #pragma unroll
  for (int mf = 0; mf < 4; ++mf) {
    #pragma unroll
    for (int v = 0; v < 4; ++v) {
      int rr = r0 + wm*64 + mf*16 + (lane >> 4)*4 + v;
      float gi  = acc[mf][0][v] + bia[0];
      float gfl = acc[mf][1][v] + bia[1];
      float gfr = acc[mf][2][v] + bia[2];
      float go  = acc[mf][3][v] + bia[3];
      float gu  = acc[mf][4][v] + bia[4];
      float cl = 0.f, cr = 0.f;
      if (cprev) {
        cl = cprev[(size_t)(2*rr)*HH + jg];
        cr = cprev[(size_t)(2*rr)*HH + HH + jg];
      }
      float cc = sigf(gi)*tanh_fast(gu) + sigf(gfl)*cl + sigf(gfr)*cr;
      float hh = sigf(go)*tanh_fast(cc);
      int b = rr >> lkshift;
      int t = rr & Lmask;
      out[((size_t)b*TOUT + sc + t)*HH + jg] = hh;
      hout[(size_t)rr*HH + jg] = __float2bfloat16(hh);
      cout[(size_t)rr*HH + jg] = cc;
    }
  }
}

extern "C" void kernel_launch(void* const* d_in, const int* in_sizes, int n_in,
                              void* d_out, int out_size, void* d_ws, size_t ws_size,
                              hipStream_t stream) {
  (void)in_sizes; (void)n_in; (void)out_size; (void)ws_size;
  const int*   tok  = (const int*)d_in[0];
  const float* emb  = (const float*)d_in[1];
  const float* Wx   = (const float*)d_in[2];
  const float* Ul   = (const float*)d_in[3];
  const float* Ur   = (const float*)d_in[4];
  const float* bias = (const float*)d_in[5];
  float* out = (float*)d_out;

  char* ws = (char*)d_ws;
  size_t off = 0;
  __hip_bfloat16* Wb0t = (__hip_bfloat16*)(ws + off); off += (size_t)NGATE*320*2;
  __hip_bfloat16* Wb1t = (__hip_bfloat16*)(ws + off); off += (size_t)NGATE*1024*2;
  __hip_bfloat16* hA   = (__hip_bfloat16*)(ws + off); off += (size_t)32768*HH*2;
  __hip_bfloat16* hB   = (__hip_bfloat16*)(ws + off); off += (size_t)16384*HH*2;
  float*          cA   = (float*)(ws + off);          off += (size_t)32768*HH*4;
  float*          cB   = (float*)(ws + off);          off += (size_t)16384*HH*4;
  __hip_bfloat16* A0   = (__hip_bfloat16*)cB;   // alias: A0 dead before cB first written

  prep_weights<<<dim3(8, 40, 3), 256, 0, stream>>>(Wx, Ul, Ur, Wb0t, Wb1t);
  embed_cvt<<<dim3(5, 8192), dim3(64,4), 0, stream>>>(tok, emb, A0);

  // levels 0..2: ring-pipelined BM=256 kernel
  gemm_big<<<(32768/256)*8, 512, 0, stream>>>(A0, Wb0t, 320, bias, nullptr,
                                              out, hA, cA, 8, 0);
  gemm_big<<<(16384/256)*8, 512, 0, stream>>>(hA, Wb1t, 1024, bias, cA,
                                              out, hB, cB, 7, 256);
  gemm_big<<<(8192/256)*8, 512, 0, stream>>>(hB, Wb1t, 1024, bias, cB,
                                             out, hA, cA, 6, 384);
  // levels 3..8: proven R7 kernel
  for (int k = 3; k <= 8; ++k) {
    int M = 32768 >> k;
    int sc = HH - (HH >> k);
    const __hip_bfloat16* Ain = (k & 1) ? hA : hB;
    __hip_bfloat16*       hO  = (k & 1) ? hB : hA;
    const float*          cI  = (k & 1) ? cA : cB;
    float*                cO  = (k & 1) ? cB : cA;
    int numM = M / 128;
    gemm_cell<<<numM*8, 512, 0, stream>>>(Ain, Wb1t, 1024, bias, cI,
                                          out, hO, cO, 8 - k, sc, numM);
  }
}

// Round 13
// 441.895 us; speedup vs baseline: 1.5789x; 1.0479x over previous
//
#include <hip/hip_runtime.h>
#include <hip/hip_bf16.h>
#include <cstdint>

#define BB 128
#define LL 256
#define DD 300
#define HH 512
#define TOUT 511
#define NGATE 2560   // 5*H

typedef __attribute__((ext_vector_type(8))) short bf16x8;
typedef __attribute__((ext_vector_type(4))) float f32x4;

__device__ __forceinline__ float rcpf(float x){ return __builtin_amdgcn_rcpf(x); }
__device__ __forceinline__ float ex2f(float x){ return __builtin_amdgcn_exp2f(x); }
__device__ __forceinline__ float sigf(float x){ return rcpf(1.0f + ex2f(x * -1.44269504f)); }
__device__ __forceinline__ float tanh_fast(float x){ return 1.0f - 2.0f*rcpf(ex2f(x * 2.88539008f) + 1.0f); }

__device__ __forceinline__ void load_lds16(const void* g, void* l) {
  __builtin_amdgcn_global_load_lds(
      (const __attribute__((address_space(1))) unsigned int*)g,
      (__attribute__((address_space(3))) unsigned int*)l, 16, 0, 0);
}

#define VMWAIT(n) asm volatile("s_waitcnt vmcnt(" #n ")" ::: "memory")
#define LGKM0()   asm volatile("s_waitcnt lgkmcnt(0)" ::: "memory")

// ---- fused weight prep
__global__ __launch_bounds__(256) void prep_weights(
    const float* __restrict__ Wx, const float* __restrict__ Ul, const float* __restrict__ Ur,
    __hip_bfloat16* __restrict__ Wb0t, __hip_bfloat16* __restrict__ Wb1t)
{
  const int z = blockIdx.z;
  const float* src; __hip_bfloat16* dst; int Ksrc, Kdst, koff;
  if (z == 0) { if (blockIdx.x >= 5) return; src = Wx; dst = Wb0t; Ksrc = DD; Kdst = 320; koff = 0; }
  else if (z == 1) { src = Ul; dst = Wb1t; Ksrc = HH; Kdst = 1024; koff = 0; }
  else { src = Ur; dst = Wb1t; Ksrc = HH; Kdst = 1024; koff = 512; }

  __shared__ float t[64][65];
  const int tid = threadIdx.x;
  const int k0 = blockIdx.x * 64;
  const int n0 = blockIdx.y * 64;
  #pragma unroll
  for (int p = 0; p < 16; ++p) {
    int lin = p*256 + tid;
    int ki = lin >> 6, nj = lin & 63;
    t[ki][nj] = (k0 + ki < Ksrc) ? src[(size_t)(k0+ki)*NGATE + n0 + nj] : 0.f;
  }
  __syncthreads();
  #pragma unroll
  for (int p = 0; p < 16; ++p) {
    int lin = p*256 + tid;
    int ni = lin >> 6, kj = lin & 63;
    dst[(size_t)(n0+ni)*Kdst + koff + k0 + kj] = __float2bfloat16(t[kj][ni]);
  }
}

__global__ void embed_cvt(const int* __restrict__ tok, const float* __restrict__ emb,
                          __hip_bfloat16* __restrict__ A0)
{
  int k = blockIdx.x * 64 + threadIdx.x;
  int r = blockIdx.y * 4 + threadIdx.y;
  int tk = tok[r];
  float v = (k < DD) ? emb[(size_t)tk*DD + k] : 0.f;
  A0[(size_t)r*320 + k] = __float2bfloat16(v);
}

// ======== BIG kernel (L0-L2, R12 unchanged): BM=256 x 64h, 4-slot ring, 3 ahead
__global__ __launch_bounds__(512, 2) void gemm_big(
    const __hip_bfloat16* __restrict__ A, const __hip_bfloat16* __restrict__ Wt,
    int K, const float* __restrict__ bias, const float* __restrict__ cprev,
    float* __restrict__ out, __hip_bfloat16* __restrict__ hout, float* __restrict__ cout,
    int lkshift, int sc)
{
  constexpr int HBYT = 36864;
  __shared__ __align__(16) char lds[4*HBYT];

  const int tid  = threadIdx.x;
  const int lane = tid & 63;
  const int wid  = tid >> 6;
  const int wm   = wid >> 2;
  const int wn   = wid & 3;
  const int bid  = blockIdx.x;
  const int m    = (bid & 7) + ((bid >> 6) << 3);
  const int s    = (bid >> 3) & 7;
  const int r0   = m * 256;
  const int n0   = s * 64;
  const size_t rowK = (size_t)K * 2;

  const int gi0 = (wid < 4) ? wid*5 : 20 + (wid-4)*4;
  const char* gsrc[5];
  #pragma unroll
  for (int i = 0; i < 5; ++i) {
    int gi = gi0 + i;
    if (gi < 16) {
      int row = gi*16 + (lane >> 2);
      int cs  = (lane & 3) ^ ((row >> 1) & 3);
      gsrc[i] = (const char*)A + (size_t)(r0 + row)*rowK + cs*16;
    } else {
      int rowb = (gi-16)*16 + (lane >> 2);
      int cs   = (lane & 3) ^ ((rowb >> 1) & 3);
      int grow = (rowb >> 6)*512 + n0 + (rowb & 63);
      gsrc[i] = (const char*)Wt + (size_t)grow*rowK + cs*16;
    }
  }
  const int ldst0 = gi0*1024 + lane*16;

  f32x4 acc[8][5];
  #pragma unroll
  for (int mf = 0; mf < 8; ++mf)
    #pragma unroll
    for (int g5 = 0; g5 < 5; ++g5)
      acc[mf][g5] = (f32x4){0.f,0.f,0.f,0.f};

  const int nt = K >> 5;
  auto stage = [&](int t){
    char* base = lds + (size_t)(t & 3)*HBYT + ldst0;
    const size_t kb = (size_t)t*64;
    if (wid < 4) {
      #pragma unroll
      for (int i = 0; i < 5; ++i) load_lds16(gsrc[i] + kb, base + i*1024);
    } else {
      #pragma unroll
      for (int i = 0; i < 4; ++i) load_lds16(gsrc[i] + kb, base + i*1024);
    }
  };

  stage(0); stage(1); stage(2);

  for (int t = 0; t < nt; ++t) {
    if (t + 2 < nt)      { if (wid < 4) VMWAIT(10); else VMWAIT(8); }
    else if (t + 1 < nt) { if (wid < 4) VMWAIT(5);  else VMWAIT(4); }
    else                 { VMWAIT(0); }
    LGKM0();
    __builtin_amdgcn_s_barrier();

    const char* Ab = lds + (size_t)(t & 3)*HBYT;
    const char* Bb = Ab + 16384;
    const int q = lane >> 4;

    bf16x8 b[5];
    #pragma unroll
    for (int g5 = 0; g5 < 5; ++g5) {
      int c = g5*64 + wn*16 + (lane & 15);
      b[g5] = *(const bf16x8*)(Bb + c*64 + ((q ^ ((c >> 1) & 3))*16));
    }
    bf16x8 a[4];
    #pragma unroll
    for (int i = 0; i < 4; ++i) {
      int r = wm*128 + i*16 + (lane & 15);
      a[i] = *(const bf16x8*)(Ab + r*64 + ((q ^ ((r >> 1) & 3))*16));
    }
    if (t + 3 < nt) stage(t + 3);
    __builtin_amdgcn_sched_barrier(0);
    __builtin_amdgcn_s_setprio(1);
    #pragma unroll
    for (int mf = 0; mf < 4; ++mf)
      #pragma unroll
      for (int g5 = 0; g5 < 5; ++g5)
        acc[mf][g5] = __builtin_amdgcn_mfma_f32_16x16x32_bf16(a[mf], b[g5], acc[mf][g5], 0, 0, 0);
    __builtin_amdgcn_s_setprio(0);

    #pragma unroll
    for (int i = 0; i < 4; ++i) {
      int r = wm*128 + (4+i)*16 + (lane & 15);
      a[i] = *(const bf16x8*)(Ab + r*64 + ((q ^ ((r >> 1) & 3))*16));
    }
    __builtin_amdgcn_sched_barrier(0);
    __builtin_amdgcn_s_setprio(1);
    #pragma unroll
    for (int mf = 0; mf < 4; ++mf)
      #pragma unroll
      for (int g5 = 0; g5 < 5; ++g5)
        acc[4+mf][g5] = __builtin_amdgcn_mfma_f32_16x16x32_bf16(a[mf], b[g5], acc[4+mf][g5], 0, 0, 0);
    __builtin_amdgcn_s_setprio(0);
  }

  const int Lmask = (1 << lkshift) - 1;
  const int jg = n0 + wn*16 + (lane & 15);
  float bia[5];
  #pragma unroll
  for (int g5 = 0; g5 < 5; ++g5) bia[g5] = bias[g5*HH + jg];
  #pragma unroll
  for (int mf = 0; mf < 8; ++mf) {
    #pragma unroll
    for (int v = 0; v < 4; ++v) {
      int rr = r0 + wm*128 + mf*16 + (lane >> 4)*4 + v;
      float gi  = acc[mf][0][v] + bia[0];
      float gfl = acc[mf][1][v] + bia[1];
      float gfr = acc[mf][2][v] + bia[2];
      float go  = acc[mf][3][v] + bia[3];
      float gu  = acc[mf][4][v] + bia[4];
      float cl = 0.f, cr = 0.f;
      if (cprev) {
        cl = cprev[(size_t)(2*rr)*HH + jg];
        cr = cprev[(size_t)(2*rr)*HH + HH + jg];
      }
      float cc = sigf(gi)*tanh_fast(gu) + sigf(gfl)*cl + sigf(gfr)*cr;
      float hh = sigf(go)*tanh_fast(cc);
      int b = rr >> lkshift;
      int t = rr & Lmask;
      out[((size_t)b*TOUT + sc + t)*HH + jg] = hh;
      hout[(size_t)rr*HH + jg] = __float2bfloat16(hh);
      cout[(size_t)rr*HH + jg] = cc;
    }
  }
}

// ======== TAIL kernel (L3-L8): BK=64 variant (R3-proven body), K=1024 fixed.
// BM=128, 2x56KB dbuf, counted vmcnt(7) — 16 latency quanta instead of 32.
__global__ __launch_bounds__(512, 2) void gemm_tail(
    const __hip_bfloat16* __restrict__ A, const __hip_bfloat16* __restrict__ Wt,
    const float* __restrict__ bias, const float* __restrict__ cprev,
    float* __restrict__ out, __hip_bfloat16* __restrict__ hout, float* __restrict__ cout,
    int lkshift, int sc, int numM)
{
  constexpr int ABYTES = 16384;          // A: 128 x 64k bf16 (128B rows)
  constexpr int BUFS   = ABYTES + 40960; // + B: 320 x 64k bf16
  __shared__ __align__(16) char lds[2*BUFS];

  const int tid  = threadIdx.x;
  const int lane = tid & 63;
  const int wid  = tid >> 6;
  const int wm   = wid >> 2;
  const int wn   = wid & 3;
  const int bid  = blockIdx.x;
  int m, s;
  if (numM >= 8) { m = (bid & 7) + ((bid >> 6) << 3); s = (bid >> 3) & 7; }
  else           { m = bid % numM;  s = bid / numM; }
  const int r0   = m * 128;
  const int n0   = s * 64;
  constexpr size_t rowK = 2048;   // K=1024 * 2B

  const int srow = lane >> 3;
  const int gq   = (lane & 7) ^ srow;
  const char* gsrc[7];
  #pragma unroll
  for (int ii = 0; ii < 7; ++ii) {
    int issue = wid*7 + ii;
    if (issue < 16) {
      int r = issue*8 + srow;
      gsrc[ii] = (const char*)A + (size_t)(r0 + r)*rowK + (size_t)gq*16;
    } else {
      int c = (issue-16)*8 + srow;
      int grow = (c >> 6)*512 + n0 + (c & 63);
      gsrc[ii] = (const char*)Wt + (size_t)grow*rowK + (size_t)gq*16;
    }
  }
  const int ldst0 = (wid*7)*1024 + lane*16;   // issue*1024 uniform (A ends at 16KB)

  f32x4 acc[4][5];
  #pragma unroll
  for (int mf = 0; mf < 4; ++mf)
    #pragma unroll
    for (int g5 = 0; g5 < 5; ++g5)
      acc[mf][g5] = (f32x4){0.f,0.f,0.f,0.f};

  auto stage = [&](int buf, int kt){
    char* base = lds + buf*BUFS + ldst0;
    const size_t kb = (size_t)kt*128;
    #pragma unroll
    for (int ii = 0; ii < 7; ++ii) load_lds16(gsrc[ii] + kb, base + ii*1024);
  };

  stage(0, 0);
  int cur = 0;
  for (int kt = 0; kt < 16; ++kt) {
    if (kt + 1 < 16) {
      stage(cur ^ 1, kt + 1);
      VMWAIT(7);
    } else {
      VMWAIT(0);
    }
    __builtin_amdgcn_s_barrier();

    const char* Ab = lds + cur*BUFS;
    const char* Bb = Ab + ABYTES;
    #pragma unroll
    for (int s2 = 0; s2 < 2; ++s2) {
      const int qb = s2*4 + (lane >> 4);
      bf16x8 b[5];
      #pragma unroll
      for (int g5 = 0; g5 < 5; ++g5) {
        int c = g5*64 + wn*16 + (lane & 15);
        b[g5] = *(const bf16x8*)(Bb + c*128 + ((qb ^ (c & 7))*16));
      }
      __builtin_amdgcn_s_setprio(1);
      #pragma unroll
      for (int mf = 0; mf < 4; ++mf) {
        int r = wm*64 + mf*16 + (lane & 15);
        bf16x8 av = *(const bf16x8*)(Ab + r*128 + ((qb ^ (r & 7))*16));
        #pragma unroll
        for (int g5 = 0; g5 < 5; ++g5)
          acc[mf][g5] = __builtin_amdgcn_mfma_f32_16x16x32_bf16(av, b[g5], acc[mf][g5], 0, 0, 0);
      }
      __builtin_amdgcn_s_setprio(0);
    }
    __builtin_amdgcn_s_barrier();
    cur ^= 1;
  }

  const int Lmask = (1 << lkshift) - 1;
  const int jg = n0 + wn*16 + (lane & 15);
  float bia[5];
  #pragma unroll
  for (int g5 = 0; g5 < 5; ++g5) bia[g5] = bias[g5*HH + jg];
  #pragma unroll
  for (int mf = 0; mf < 4; ++mf) {
    #pragma unroll
    for (int v = 0; v < 4; ++v) {
      int rr = r0 + wm*64 + mf*16 + (lane >> 4)*4 + v;
      float gi  = acc[mf][0][v] + bia[0];
      float gfl = acc[mf][1][v] + bia[1];
      float gfr = acc[mf][2][v] + bia[2];
      float go  = acc[mf][3][v] + bia[3];
      float gu  = acc[mf][4][v] + bia[4];
      float cl = cprev[(size_t)(2*rr)*HH + jg];
      float cr = cprev[(size_t)(2*rr)*HH + HH + jg];
      float cc = sigf(gi)*tanh_fast(gu) + sigf(gfl)*cl + sigf(gfr)*cr;
      float hh = sigf(go)*tanh_fast(cc);
      int b = rr >> lkshift;
      int t = rr & Lmask;
      out[((size_t)b*TOUT + sc + t)*HH + jg] = hh;
      hout[(size_t)rr*HH + jg] = __float2bfloat16(hh);
      cout[(size_t)rr*HH + jg] = cc;
    }
  }
}

extern "C" void kernel_launch(void* const* d_in, const int* in_sizes, int n_in,
                              void* d_out, int out_size, void* d_ws, size_t ws_size,
                              hipStream_t stream) {
  (void)in_sizes; (void)n_in; (void)out_size; (void)ws_size;
  const int*   tok  = (const int*)d_in[0];
  const float* emb  = (const float*)d_in[1];
  const float* Wx   = (const float*)d_in[2];
  const float* Ul   = (const float*)d_in[3];
  const float* Ur   = (const float*)d_in[4];
  const float* bias = (const float*)d_in[5];
  float* out = (float*)d_out;

  char* ws = (char*)d_ws;
  size_t off = 0;
  __hip_bfloat16* Wb0t = (__hip_bfloat16*)(ws + off); off += (size_t)NGATE*320*2;
  __hip_bfloat16* Wb1t = (__hip_bfloat16*)(ws + off); off += (size_t)NGATE*1024*2;
  __hip_bfloat16* hA   = (__hip_bfloat16*)(ws + off); off += (size_t)32768*HH*2;
  __hip_bfloat16* hB   = (__hip_bfloat16*)(ws + off); off += (size_t)16384*HH*2;
  float*          cA   = (float*)(ws + off);          off += (size_t)32768*HH*4;
  float*          cB   = (float*)(ws + off);          off += (size_t)16384*HH*4;
  __hip_bfloat16* A0   = (__hip_bfloat16*)cB;   // alias: A0 dead before cB first written

  prep_weights<<<dim3(8, 40, 3), 256, 0, stream>>>(Wx, Ul, Ur, Wb0t, Wb1t);
  embed_cvt<<<dim3(5, 8192), dim3(64,4), 0, stream>>>(tok, emb, A0);

  // levels 0..2: R12 ring kernel (unchanged baseline)
  gemm_big<<<(32768/256)*8, 512, 0, stream>>>(A0, Wb0t, 320, bias, nullptr,
                                              out, hA, cA, 8, 0);
  gemm_big<<<(16384/256)*8, 512, 0, stream>>>(hA, Wb1t, 1024, bias, cA,
                                              out, hB, cB, 7, 256);
  gemm_big<<<(8192/256)*8, 512, 0, stream>>>(hB, Wb1t, 1024, bias, cB,
                                             out, hA, cA, 6, 384);
  // levels 3..8: BK=64 tail variant (A/B vs R12's BK=32 tail)
  for (int k = 3; k <= 8; ++k) {
    int M = 32768 >> k;
    int sc = HH - (HH >> k);
    const __hip_bfloat16* Ain = (k & 1) ? hA : hB;
    __hip_bfloat16*       hO  = (k & 1) ? hB : hA;
    const float*          cI  = (k & 1) ? cA : cB;
    float*                cO  = (k & 1) ? cB : cA;
    int numM = M / 128;
    gemm_tail<<<numM*8, 512, 0, stream>>>(Ain, Wb1t, bias, cI,
                                          out, hO, cO, 8 - k, sc, numM);
  }
}